// Round 1
// baseline (604.569 us; speedup 1.0000x reference)
//
#include <hip/hip_runtime.h>

// LightGCN propagation on MI355X.
// y[r,:] = sum_{e: row[e]==r} val[e] * h[col[e],:]   (COO SpMM, D=32)
// out = (x + h1 + h2 + h3) / 4
//
// Round 1 strategy: atomic scatter SpMM. One thread per (edge, d) so each
// half-wave (32 lanes) handles one edge: coalesced 128B gather of h[col],
// 32 consecutive-address fp32 atomicAdds (distinct addresses within the
// cacheline -> no intra-wave serialization).

#define NN 100000
#define NE 1600000
#define DD 32

__global__ __launch_bounds__(256) void spmm_atomic(
    const int* __restrict__ row, const int* __restrict__ col,
    const float* __restrict__ val, const float* __restrict__ h,
    float* __restrict__ out)
{
    long long idx = (long long)blockIdx.x * blockDim.x + threadIdx.x;
    int e = (int)(idx >> 5);
    int d = (int)(idx & 31);
    if (e >= NE) return;
    int r = row[e];
    int c = col[e];
    float v = val[e];
    atomicAdd(&out[(long long)r * DD + d], v * h[(long long)c * DD + d]);
}

// out = a + b (elementwise, float4-vectorized). Aliasing out==a is fine.
__global__ __launch_bounds__(256) void add2(
    const float4* __restrict__ a, const float4* __restrict__ b,
    float4* __restrict__ out, int n4)
{
    int i = blockIdx.x * blockDim.x + threadIdx.x;
    if (i >= n4) return;
    float4 x = a[i];
    float4 y = b[i];
    out[i] = make_float4(x.x + y.x, x.y + y.y, x.z + y.z, x.w + y.w);
}

// out = (a + b) * s
__global__ __launch_bounds__(256) void add2_scale(
    const float4* __restrict__ a, const float4* __restrict__ b,
    float4* __restrict__ out, int n4, float s)
{
    int i = blockIdx.x * blockDim.x + threadIdx.x;
    if (i >= n4) return;
    float4 x = a[i];
    float4 y = b[i];
    out[i] = make_float4((x.x + y.x) * s, (x.y + y.y) * s,
                         (x.z + y.z) * s, (x.w + y.w) * s);
}

extern "C" void kernel_launch(void* const* d_in, const int* in_sizes, int n_in,
                              void* d_out, int out_size, void* d_ws, size_t ws_size,
                              hipStream_t stream) {
    const int*   edge_row = (const int*)d_in[0];
    const int*   edge_col = (const int*)d_in[1];
    const float* edge_val = (const float*)d_in[2];
    const float* x        = (const float*)d_in[3];
    float* out = (float*)d_out;

    const size_t nd       = (size_t)NN * DD;           // 3.2M floats
    const size_t nd_bytes = nd * sizeof(float);        // 12.8 MB
    float* buf0 = (float*)d_ws;
    float* buf1 = (float*)((char*)d_ws + nd_bytes);

    const int n4 = (int)(nd / 4);                      // 800k float4
    dim3 ew_grid((n4 + 255) / 256);
    const long long spmm_threads = (long long)NE * DD; // 51.2M
    dim3 sp_grid((unsigned)((spmm_threads + 255) / 256));

    // layer 1: h1 = A x ; out = x + h1
    hipMemsetAsync(buf0, 0, nd_bytes, stream);
    spmm_atomic<<<sp_grid, 256, 0, stream>>>(edge_row, edge_col, edge_val, x, buf0);
    add2<<<ew_grid, 256, 0, stream>>>((const float4*)x, (const float4*)buf0,
                                      (float4*)out, n4);

    // layer 2: h2 = A h1 ; out += h2
    hipMemsetAsync(buf1, 0, nd_bytes, stream);
    spmm_atomic<<<sp_grid, 256, 0, stream>>>(edge_row, edge_col, edge_val, buf0, buf1);
    add2<<<ew_grid, 256, 0, stream>>>((const float4*)out, (const float4*)buf1,
                                      (float4*)out, n4);

    // layer 3: h3 = A h2 ; out = (out + h3) * 0.25
    hipMemsetAsync(buf0, 0, nd_bytes, stream);
    spmm_atomic<<<sp_grid, 256, 0, stream>>>(edge_row, edge_col, edge_val, buf1, buf0);
    add2_scale<<<ew_grid, 256, 0, stream>>>((const float4*)out, (const float4*)buf0,
                                            (float4*)out, n4, 0.25f);
}

// Round 2
// 425.358 us; speedup vs baseline: 1.4213x; 1.4213x over previous
//
#include <hip/hip_runtime.h>

// LightGCN propagation on MI355X (gfx950).
//   h_{k+1}[r,:] = sum_{e: row[e]==r} val[e] * h_k[col[e],:]   D=32
//   out = (x + h1 + h2 + h3) / 4
//
// Round 2: R1's atomic-scatter SpMM was atomic-RMW-bound (WRITE_SIZE = E*D*4
// = 204.8 MB per layer -> every fp32 atomicAdd is an individual memory RMW).
// Replace with CSR gather-reduce built on the fly each call:
//   histogram -> block scan -> small scan -> add offsets -> scatter pack
// then 3 fused SpMM layers: one 32-lane half-wave per row, register
// accumulate, single write per output element. Layer accumulation into
// d_out is fused into the SpMM epilogue (row ownership -> no atomics).

#define NN 100000
#define NE 1600000
#define DD 32
#define NB ((NN + 255) / 256)   // 391 scan blocks

// ---- CSR build ------------------------------------------------------------

__global__ __launch_bounds__(256) void hist_kernel(
    const int* __restrict__ row, int* __restrict__ deg)
{
    int e = blockIdx.x * 256 + threadIdx.x;
    if (e < NE) atomicAdd(&deg[row[e]], 1);
}

// In-place: data[i] (degree) -> exclusive scan within this 256-block;
// bsum[b] = block total.
__global__ __launch_bounds__(256) void block_scan_kernel(
    int* __restrict__ data, int* __restrict__ bsum, int n)
{
    int i = blockIdx.x * 256 + threadIdx.x;
    int v = (i < n) ? data[i] : 0;
    int lane = threadIdx.x & 63;
    int wid  = threadIdx.x >> 6;
    int x = v;
    #pragma unroll
    for (int off = 1; off < 64; off <<= 1) {
        int y = __shfl_up(x, off, 64);
        if (lane >= off) x += y;
    }
    __shared__ int wtot[4];
    if (lane == 63) wtot[wid] = x;
    __syncthreads();
    int wo = 0;
    #pragma unroll
    for (int w = 0; w < 4; w++) if (w < wid) wo += wtot[w];
    int incl = x + wo;
    if (i < n) data[i] = incl - v;                  // exclusive within block
    if (threadIdx.x == 255) bsum[blockIdx.x] = incl; // block total
}

// Exclusive scan of <=512 elements in one block (the 391 block totals).
__global__ __launch_bounds__(512) void small_scan_kernel(
    int* __restrict__ data, int n)
{
    int i = threadIdx.x;
    int v = (i < n) ? data[i] : 0;
    int lane = i & 63, wid = i >> 6;
    int x = v;
    #pragma unroll
    for (int off = 1; off < 64; off <<= 1) {
        int y = __shfl_up(x, off, 64);
        if (lane >= off) x += y;
    }
    __shared__ int wtot[8];
    if (lane == 63) wtot[wid] = x;
    __syncthreads();
    int wo = 0;
    #pragma unroll
    for (int w = 0; w < 8; w++) if (w < wid) wo += wtot[w];
    int incl = x + wo;
    if (i < n) data[i] = incl - v;                  // exclusive
}

__global__ __launch_bounds__(256) void add_offsets_kernel(
    const int* __restrict__ scanned, const int* __restrict__ bsum,
    int* __restrict__ row_ptr, int* __restrict__ cursor, int n)
{
    int i = blockIdx.x * 256 + threadIdx.x;
    if (i < n) {
        int v = scanned[i] + bsum[blockIdx.x];
        row_ptr[i] = v;
        cursor[i]  = v;
    }
    if (i == 0) row_ptr[n] = NE;
}

__global__ __launch_bounds__(256) void scatter_kernel(
    const int* __restrict__ row, const int* __restrict__ col,
    const float* __restrict__ val, int* __restrict__ cursor,
    int2* __restrict__ edges)
{
    int e = blockIdx.x * 256 + threadIdx.x;
    if (e < NE) {
        int r = row[e];
        int pos = atomicAdd(&cursor[r], 1);
        edges[pos] = make_int2(col[e], __float_as_int(val[e]));
    }
}

// ---- fused CSR SpMM layers ------------------------------------------------
// One 32-lane half-wave per row; lane d owns feature d. Edge record is a
// single broadcast int2 load. MODE 0: hout=Ax, out=x+Ax. MODE 1: hout=Ah,
// out+=Ah. MODE 2 (last): out=(out+Ah)*0.25, hout unused.

template <int MODE>
__global__ __launch_bounds__(256) void spmm_csr_kernel(
    const int* __restrict__ row_ptr, const int2* __restrict__ edges,
    const float* __restrict__ hin, float* __restrict__ hout,
    const float* __restrict__ xin, float* __restrict__ out)
{
    int g = blockIdx.x * 8 + (threadIdx.x >> 5);   // row
    if (g >= NN) return;
    int d = threadIdx.x & 31;
    int s = row_ptr[g];
    int e = row_ptr[g + 1];
    float acc = 0.f;
    int i = s;
    for (; i + 2 <= e; i += 2) {                   // 2x unroll for MLP
        int2 e0 = edges[i];
        int2 e1 = edges[i + 1];
        float a0 = hin[(size_t)e0.x * DD + d];
        float a1 = hin[(size_t)e1.x * DD + d];
        acc += __int_as_float(e0.y) * a0;
        acc += __int_as_float(e1.y) * a1;
    }
    if (i < e) {
        int2 e0 = edges[i];
        acc += __int_as_float(e0.y) * hin[(size_t)e0.x * DD + d];
    }
    size_t o = (size_t)g * DD + d;
    if (MODE == 0)      { hout[o] = acc; out[o] = xin[o] + acc; }
    else if (MODE == 1) { hout[o] = acc; out[o] = out[o] + acc; }
    else                { out[o] = (out[o] + acc) * 0.25f; }
}

// ---- launch ---------------------------------------------------------------

extern "C" void kernel_launch(void* const* d_in, const int* in_sizes, int n_in,
                              void* d_out, int out_size, void* d_ws, size_t ws_size,
                              hipStream_t stream) {
    const int*   edge_row = (const int*)d_in[0];
    const int*   edge_col = (const int*)d_in[1];
    const float* edge_val = (const float*)d_in[2];
    const float* x        = (const float*)d_in[3];
    float* out = (float*)d_out;

    // workspace layout
    char* ws = (char*)d_ws;
    int*  deg     = (int*)ws;                 ws += ((size_t)NN * 4 + 511) & ~511ull;      // scratch / scanned
    int*  row_ptr = (int*)ws;                 ws += ((size_t)(NN + 1) * 4 + 511) & ~511ull;
    int*  cursor  = (int*)ws;                 ws += ((size_t)NN * 4 + 511) & ~511ull;
    int*  bsum    = (int*)ws;                 ws += 4096;
    int2* edges   = (int2*)ws;                ws += (size_t)NE * 8;                        // 12.8 MB
    float* h0     = (float*)ws;               ws += (size_t)NN * DD * 4;                   // 12.8 MB
    float* h1     = (float*)ws;               /* ws += 12.8 MB */

    // CSR build
    hipMemsetAsync(deg, 0, (size_t)NN * 4, stream);
    hist_kernel      <<<(NE + 255) / 256, 256, 0, stream>>>(edge_row, deg);
    block_scan_kernel<<<NB, 256, 0, stream>>>(deg, bsum, NN);
    small_scan_kernel<<<1, 512, 0, stream>>>(bsum, NB);
    add_offsets_kernel<<<NB, 256, 0, stream>>>(deg, bsum, row_ptr, cursor, NN);
    scatter_kernel   <<<(NE + 255) / 256, 256, 0, stream>>>(edge_row, edge_col,
                                                            edge_val, cursor, edges);

    // 3 fused propagation layers (8 rows per 256-thread block)
    dim3 sp_grid((NN + 7) / 8);
    spmm_csr_kernel<0><<<sp_grid, 256, 0, stream>>>(row_ptr, edges, x,  h0, x, out);
    spmm_csr_kernel<1><<<sp_grid, 256, 0, stream>>>(row_ptr, edges, h0, h1, x, out);
    spmm_csr_kernel<2><<<sp_grid, 256, 0, stream>>>(row_ptr, edges, h1, h0, x, out);
}